// Round 6
// baseline (137.777 us; speedup 1.0000x reference)
//
#include <hip/hip_runtime.h>
#include <hip/hip_bf16.h>

#define B_  8
#define T_  2048
#define E_  1024
#define H_  64
#define BT_ (B_*T_)

typedef __attribute__((ext_vector_type(8))) __bf16 bf16x8;
typedef __attribute__((ext_vector_type(4))) float  f32x4;

__device__ __forceinline__ unsigned short f2bfu(float f) {
    union { float f; unsigned u; } v; v.f = f;
    unsigned r = v.u + 0x7fffu + ((v.u >> 16) & 1u);
    return (unsigned short)(r >> 16);
}

__device__ __forceinline__ unsigned pk2(float lo, float hi) {
    __hip_bfloat162 h = __float22bfloat162_rn(float2{lo, hi});
    union { __hip_bfloat162 h; unsigned u; } v; v.h = h;
    return v.u;
}

// Q pre-scale: 1/sqrt(H) * log2(e)  (attn softmax runs in exp2 domain)
#define QSCALE (0.125f * 1.44269504f)

// ---------------- Phase 0: W -> fragment-major swizzled W^T (bf16) ----------
// wf layout: [c2(32 k-chunks of 32)][m(3)][n(4 h-tiles)][lane(64)][j(8)]
// => B-fragment for (k-chunk c2, tile j=m*4+n) is the contiguous 1 KB at
//    (c2*12 + j)*512 shorts: a wave reads it as base + lane*16 (coalesced).
__global__ __launch_bounds__(256)
void wprep_kernel(const float* __restrict__ Wq,
                  const float* __restrict__ Wk,
                  const float* __restrict__ Wv,
                  unsigned short* __restrict__ wf)
{
    const int c = blockIdx.x / 3;
    const int m = blockIdx.x % 3;
    const float* W = (m == 0) ? Wq : (m == 1 ? Wk : Wv);
    const float scale = (m == 0) ? QSCALE : 1.0f;

    const int n    = threadIdx.x >> 6;
    const int lane = threadIdx.x & 63;
    const int quad = lane >> 4;
    const int col  = lane & 15;
    const int h    = n * 16 + col;

    unsigned short tmp[8];
#pragma unroll
    for (int j = 0; j < 8; ++j)
        tmp[j] = f2bfu(W[(c * 32 + quad * 8 + j) * H_ + h] * scale);
    *(uint4*)&wf[(((c * 3 + m) * 4 + n) * 64 + lane) * 8] = *(uint4*)tmp;
}

// ---------------- Phase 1: QKV projection, B direct global->reg -----------
// Block = 32 tokens, 4 waves, grid 512 (2 blocks/CU). Wave (mw=w&1, nh=w>>1)
// owns 6 of the 12 (mat,n) output tiles for 16 rows.
// B-fragments are read DIRECTLY from the fragment-major wf (1 KB coalesced
// wave-reads, L2/L1-resident), double-buffered in registers, staggered per
// kk-half. Only x goes through LDS (fp32->bf16 transpose), so the barrier is
// a raw s_barrier + lgkmcnt(0): B loads stay in flight across it (no vmcnt
// drain — this was the serializer in the DMA version).
__global__ __launch_bounds__(256, 2)
void qkv_kernel(const float* __restrict__ x,
                const unsigned short* __restrict__ wf,
                unsigned short* __restrict__ qb,
                unsigned short* __restrict__ kf,
                unsigned short* __restrict__ vf)
{
    __shared__ __align__(16) unsigned short xs[2][32 * 72];   // 9 KB

    const int tid  = threadIdx.x;
    const int w    = tid >> 6;
    const int lane = tid & 63;
    const int quad = lane >> 4;
    const int col  = lane & 15;
    const int mw   = w & 1;         // token-tile within block
    const int nh   = w >> 1;        // n-half: 6 tiles of the 12 (3 mats x 4)
    const long r0  = (long)blockIdx.x * 32;

    f32x4 acc[6];
#pragma unroll
    for (int i = 0; i < 6; ++i) acc[i] = (f32x4){0.f, 0.f, 0.f, 0.f};

    // x staging: thread t handles token row t>>3, k-cols (t&7)*8 .. +7
    const int row = tid >> 3;
    const int kc  = (tid & 7) * 8;
    const float* xp = x + (r0 + row) * E_ + kc;

    const unsigned short* wfl = wf + lane * 8;   // per-lane fragment base
    const int jb = nh * 6;                       // first tile index of this wave

    // ---- prologue: stage xs[0] (chunk 0), prefetch x (chunk 1), B (chunk 0)
    float4 xa[2], xb[2];
    xa[0] = *(const float4*)xp;
    xa[1] = *(const float4*)(xp + 4);
    {
        unsigned u[4] = { pk2(xa[0].x, xa[0].y), pk2(xa[0].z, xa[0].w),
                          pk2(xa[1].x, xa[1].y), pk2(xa[1].z, xa[1].w) };
        *(uint4*)&xs[0][row * 72 + kc] = *(uint4*)u;
    }
    xa[0] = *(const float4*)(xp + 64);
    xa[1] = *(const float4*)(xp + 68);
    xb[0] = xa[0]; xb[1] = xa[1];

    bf16x8 b0[6], b1[6];
#pragma unroll
    for (int i = 0; i < 6; ++i) {
        b0[i] = *(const bf16x8*)&wfl[(long)(0 * 12 + jb + i) * 512];
        b1[i] = *(const bf16x8*)&wfl[(long)(1 * 12 + jb + i) * 512];
    }

#pragma unroll 4
    for (int c = 0; c < 16; ++c) {
        const int buf = c & 1;
        // raw barrier: drain LDS ops only; B/x global loads stay in flight
        asm volatile("s_waitcnt lgkmcnt(0)" ::: "memory");
        __builtin_amdgcn_s_barrier();
        asm volatile("" ::: "memory");

        // kk = 0 half: compute, then refill b0 for chunk c+1
        bf16x8 af0 = *(const bf16x8*)&xs[buf][(mw * 16 + col) * 72 + quad * 8];
#pragma unroll
        for (int i = 0; i < 6; ++i)
            acc[i] = __builtin_amdgcn_mfma_f32_16x16x32_bf16(af0, b0[i], acc[i], 0, 0, 0);
        if (c + 1 < 16) {
#pragma unroll
            for (int i = 0; i < 6; ++i)
                b0[i] = *(const bf16x8*)&wfl[(long)((2 * c + 2) * 12 + jb + i) * 512];
        }

        // kk = 1 half: compute, then refill b1 for chunk c+1
        bf16x8 af1 = *(const bf16x8*)&xs[buf][(mw * 16 + col) * 72 + 32 + quad * 8];
#pragma unroll
        for (int i = 0; i < 6; ++i)
            acc[i] = __builtin_amdgcn_mfma_f32_16x16x32_bf16(af1, b1[i], acc[i], 0, 0, 0);
        if (c + 1 < 16) {
#pragma unroll
            for (int i = 0; i < 6; ++i)
                b1[i] = *(const bf16x8*)&wfl[(long)((2 * c + 3) * 12 + jb + i) * 512];
        }

        if (c + 1 < 16) {             // write x(c+1) into the other buffer
            unsigned u[4] = { pk2(xa[0].x, xa[0].y), pk2(xa[0].z, xa[0].w),
                              pk2(xa[1].x, xa[1].y), pk2(xa[1].z, xa[1].w) };
            *(uint4*)&xs[buf ^ 1][row * 72 + kc] = *(uint4*)u;
        }
        if (c + 2 < 16) {             // x global prefetch, ~1.5 iterations ahead
            xb[0] = *(const float4*)(xp + (c + 2) * 64);
            xb[1] = *(const float4*)(xp + (c + 2) * 64 + 4);
        }
        xa[0] = xb[0]; xa[1] = xb[1];
    }

    // epilogue: acc element = D[token = r0+mw*16+quad*4+r][h = (j&3)*16+col]
#pragma unroll
    for (int i = 0; i < 6; ++i) {
        const int j   = jb + i;           // 0..11 = mat*4 + n
        const int mat = j >> 2;           // wave-uniform
        const int h   = (j & 3) * 16 + col;
#pragma unroll
        for (int r = 0; r < 4; ++r) {
            long t = r0 + mw * 16 + quad * 4 + r;   // global token (incl. batch)
            unsigned short val = f2bfu(acc[i][r]);
            if (mat == 0) {
                qb[t * H_ + h] = val;               // scale folded into Wq
            } else if (mat == 1) {
                // fragment-major K
                long t16 = t >> 4;  int cc = (int)(t & 15);
                int half = h >> 5, qq = (h >> 3) & 3, jj = h & 7;
                kf[((t16 * 2 + half) * 64 + qq * 16 + cc) * 8 + jj] = val;
            } else {
                // fragment-major V (transposed consumption)
                long sg = t >> 6;
                int hi = (int)((t >> 5) & 1), q2 = (int)((t >> 3) & 3), j2 = (int)(t & 7);
                int n2 = h >> 4, c2 = h & 15;
                vf[(((sg * 4 + n2) * 2 + hi) * 64 + q2 * 16 + c2) * 8 + j2] = val;
            }
        }
    }
}

// ---------------- Phase 2: split-K flash attention (swapped QK^T, O^T PV) --
// Grid = 1024: block (b = bid&7 -> XCD pin, qt = 127 - bid>>3, heavy first).
// 256 threads = 4 waves = 4 split-K groups; wave g: key-tiles s = g, g+4, ...
// S^T = mfma(K, Q): lane holds S[key=kt*16+quad*4+r][q=col] -> softmax
// reduce = in-lane + 2 shfl. PV computed transposed: O^T = mfma(V^T, P).
// K/V read from FRAGMENT-MAJOR buffers: every load is base + lane*16 ->
// contiguous 1KB per wave instr (16 cachelines, not 64).
#define PSS 72

__global__ __launch_bounds__(256, 4)
void attn_kernel(const unsigned short* __restrict__ qb,
                 const unsigned short* __restrict__ kf,
                 const unsigned short* __restrict__ vf,
                 float* __restrict__ out)
{
    // overlay: ps (9 KB, K-loop) shares space with oc (17 KB, combine)
    __shared__ __align__(16) char smem[4 * 64 * 17 * 4 + 4 * 2 * 16 * 4];  // 17.9 KB
    unsigned short* ps = (unsigned short*)smem;               // [4][16 q][PSS key]
    float* oc = (float*)smem;                                 // [4][64 h][17 q-pad]
    float* ml = (float*)(smem + 4 * 64 * 17 * 4);             // [4][2][16]

    const int tid  = threadIdx.x;
    const int g    = tid >> 6;        // wave = split-K group (0..3)
    const int lane = tid & 63;
    const int quad = lane >> 4;
    const int col  = lane & 15;
    const int b    = blockIdx.x & 7;        // batch -> XCD pinning
    const int qt   = 127 - (blockIdx.x >> 3); // heavy q-tiles dispatch first
    const int nt   = (qt + 4) >> 2;         // ceil((qt+1)/4) key tiles

    const unsigned short* qbb = qb + (long)b * T_ * H_;
    const unsigned short* kfb = kf + (long)b * 128 * 2 * 512;  // 128 t16 x 2 half x 512
    const unsigned short* vfb = vf + (long)b * 32 * 4 * 2 * 512; // 32 s x 4 n x 2 hi x 512

    // Q fragment: Q[q=col][d=quad*8+j] — valid as either A or B operand
    bf16x8 qa0 = *(const bf16x8*)&qbb[(qt * 16 + col) * H_ + quad * 8];
    bf16x8 qa1 = *(const bf16x8*)&qbb[(qt * 16 + col) * H_ + 32 + quad * 8];

    f32x4 o[4];                       // O^T: o[n][r] = O[q=col][h=n*16+quad*4+r]
    float m_i = -1e30f, l_i = 0.f;    // per-lane: q-row = col
#pragma unroll
    for (int n = 0; n < 4; ++n) o[n] = (f32x4){0.f, 0.f, 0.f, 0.f};

    // K fragment prefetch for first tile (coalesced: base + lane*16)
    bf16x8 kr[8];
    if (g < nt) {
#pragma unroll
        for (int kt = 0; kt < 4; ++kt) {
            const unsigned short* kp = kfb + ((long)(g * 4 + kt) * 2) * 512 + lane * 8;
            kr[kt * 2]     = *(const bf16x8*)kp;
            kr[kt * 2 + 1] = *(const bf16x8*)(kp + 512);
        }
    }

    for (int s = g; s < nt; s += 4) {
        // S^T = K Q^T : sa[kt][r] = S[key = s*64 + kt*16 + quad*4 + r][q = col]
        f32x4 sa[4];
#pragma unroll
        for (int kt = 0; kt < 4; ++kt) {
            sa[kt] = (f32x4){0.f, 0.f, 0.f, 0.f};
            sa[kt] = __builtin_amdgcn_mfma_f32_16x16x32_bf16(kr[kt * 2],     qa0, sa[kt], 0, 0, 0);
            sa[kt] = __builtin_amdgcn_mfma_f32_16x16x32_bf16(kr[kt * 2 + 1], qa1, sa[kt], 0, 0, 0);
        }

        // hoist V(s) loads: ~softmax-duration ahead of the PV use (coalesced)
        // vr[n*2+hi] lane(q,c)[j] = V[t=s*64+hi*32+q*8+j][h=n*16+c]
        bf16x8 vr[8];
#pragma unroll
        for (int n = 0; n < 4; ++n) {
            const unsigned short* vp = vfb + ((long)(s * 4 + n) * 2) * 512 + lane * 8;
            vr[n * 2]     = *(const bf16x8*)vp;
            vr[n * 2 + 1] = *(const bf16x8*)(vp + 512);
        }

        // prefetch next tile's K (overlaps softmax + PV below)
        if (s + 4 < nt) {
#pragma unroll
            for (int kt = 0; kt < 4; ++kt) {
                const unsigned short* kp = kfb + ((long)((s + 4) * 4 + kt) * 2) * 512 + lane * 8;
                kr[kt * 2]     = *(const bf16x8*)kp;
                kr[kt * 2 + 1] = *(const bf16x8*)(kp + 512);
            }
        }

        if (s == nt - 1) {            // diagonal tile: causal mask
            const int qg = qt * 16 + col;
#pragma unroll
            for (int kt = 0; kt < 4; ++kt)
#pragma unroll
                for (int r = 0; r < 4; ++r) {
                    int kg = s * 64 + kt * 16 + quad * 4 + r;
                    if (kg > qg) sa[kt][r] = -1e30f;
                }
        }

        // online softmax: in-lane over 16 keys, then 2 shfl rounds (quads)
        float mx = fmaxf(
            fmaxf(fmaxf(fmaxf(sa[0][0], sa[0][1]), fmaxf(sa[0][2], sa[0][3])),
                  fmaxf(fmaxf(sa[1][0], sa[1][1]), fmaxf(sa[1][2], sa[1][3]))),
            fmaxf(fmaxf(fmaxf(sa[2][0], sa[2][1]), fmaxf(sa[2][2], sa[2][3])),
                  fmaxf(fmaxf(sa[3][0], sa[3][1]), fmaxf(sa[3][2], sa[3][3]))));
        mx = fmaxf(mx, __shfl_xor(mx, 16, 64));
        mx = fmaxf(mx, __shfl_xor(mx, 32, 64));

        const float mnew  = fmaxf(m_i, mx);
        const float alpha = __builtin_amdgcn_exp2f(m_i - mnew);
        m_i = mnew;

        // P = exp2(S - m); write [q][key] rows: 4x ds_write_b64
        float rs = 0.f;
#pragma unroll
        for (int kt = 0; kt < 4; ++kt) {
            float pv0 = __builtin_amdgcn_exp2f(sa[kt][0] - mnew);
            float pv1 = __builtin_amdgcn_exp2f(sa[kt][1] - mnew);
            float pv2 = __builtin_amdgcn_exp2f(sa[kt][2] - mnew);
            float pv3 = __builtin_amdgcn_exp2f(sa[kt][3] - mnew);
            rs += (pv0 + pv1) + (pv2 + pv3);
            uint2 u = { pk2(pv0, pv1), pk2(pv2, pv3) };
            *(uint2*)&ps[g * 16 * PSS + col * PSS + kt * 16 + quad * 4] = u;
        }
        rs += __shfl_xor(rs, 16, 64);
        rs += __shfl_xor(rs, 32, 64);
        l_i = l_i * alpha + rs;

        // rescale O^T: alpha is per-q = per-lane (col) — no shfl needed
#pragma unroll
        for (int n = 0; n < 4; ++n)
#pragma unroll
            for (int r = 0; r < 4; ++r)
                o[n][r] *= alpha;

        // O^T += V^T P^T : A = V^T (regs), B = P[q=col][k] from per-wave LDS
        bf16x8 pa0 = *(const bf16x8*)&ps[g * 16 * PSS + col * PSS + quad * 8];
        bf16x8 pa1 = *(const bf16x8*)&ps[g * 16 * PSS + col * PSS + 32 + quad * 8];
#pragma unroll
        for (int n = 0; n < 4; ++n) {
            o[n] = __builtin_amdgcn_mfma_f32_16x16x32_bf16(vr[n * 2],     pa0, o[n], 0, 0, 0);
            o[n] = __builtin_amdgcn_mfma_f32_16x16x32_bf16(vr[n * 2 + 1], pa1, o[n], 0, 0, 0);
        }
    }

    // ---- split-K combine (oc overlays ps -> barrier first) ----
    __syncthreads();
#pragma unroll
    for (int n = 0; n < 4; ++n)
#pragma unroll
        for (int r = 0; r < 4; ++r)
            oc[(g * 64 + n * 16 + quad * 4 + r) * 17 + col] = o[n][r];
    if (quad == 0) {                  // m/l live at q = col
        ml[(g * 2 + 0) * 16 + col] = m_i;
        ml[(g * 2 + 1) * 16 + col] = l_i;
    }
    __syncthreads();

    // merge: wave g owns q-rows g*4 .. g*4+3; lane = h (0..63)
#pragma unroll
    for (int rr = 0; rr < 4; ++rr) {
        int row = g * 4 + rr;
        float M = ml[0 * 32 + row];
#pragma unroll
        for (int j = 1; j < 4; ++j) M = fmaxf(M, ml[j * 32 + row]);
        float lsum = 0.f, osum = 0.f;
#pragma unroll
        for (int j = 0; j < 4; ++j) {
            float wgt = __builtin_amdgcn_exp2f(ml[j * 32 + row] - M);
            lsum += ml[j * 32 + 16 + row] * wgt;
            osum += oc[(j * 64 + lane) * 17 + row] * wgt;
        }
        out[((long)b * T_ + qt * 16 + row) * H_ + lane] = osum / lsum;
    }
}

extern "C" void kernel_launch(void* const* d_in, const int* in_sizes, int n_in,
                              void* d_out, int out_size, void* d_ws, size_t ws_size,
                              hipStream_t stream) {
    (void)in_sizes; (void)n_in; (void)out_size; (void)ws_size;
    const float* x  = (const float*)d_in[0];
    const float* Wq = (const float*)d_in[1];
    const float* Wk = (const float*)d_in[2];
    const float* Wv = (const float*)d_in[3];

    unsigned short* qb = (unsigned short*)d_ws;                // 2 MB row-major Q
    unsigned short* kf = qb + (size_t)BT_ * H_;                // 2 MB fragment-major K
    unsigned short* vf = kf + (size_t)BT_ * H_;                // 2 MB fragment-major V
    unsigned short* wf = vf + (size_t)BT_ * H_;                // 384 KB fragment-major W

    wprep_kernel<<<96, 256, 0, stream>>>(Wq, Wk, Wv, wf);
    qkv_kernel<<<BT_ / 32, 256, 0, stream>>>(x, wf, qb, kf, vf);
    attn_kernel<<<B_ * 128, 256, 0, stream>>>(qb, kf, vf, (float*)d_out);
}

// Round 7
// 127.851 us; speedup vs baseline: 1.0776x; 1.0776x over previous
//
#include <hip/hip_runtime.h>
#include <hip/hip_bf16.h>

#define B_  8
#define T_  2048
#define E_  1024
#define H_  64
#define BT_ (B_*T_)

typedef __attribute__((ext_vector_type(8))) __bf16 bf16x8;
typedef __attribute__((ext_vector_type(4))) float  f32x4;

__device__ __forceinline__ unsigned short f2bfu(float f) {
    union { float f; unsigned u; } v; v.f = f;
    unsigned r = v.u + 0x7fffu + ((v.u >> 16) & 1u);
    return (unsigned short)(r >> 16);
}

__device__ __forceinline__ unsigned pk2(float lo, float hi) {
    __hip_bfloat162 h = __float22bfloat162_rn(float2{lo, hi});
    union { __hip_bfloat162 h; unsigned u; } v; v.h = h;
    return v.u;
}

// async global->LDS DMA, 16B/lane. lds_base must be wave-uniform; HW writes
// lane i at lds_base + i*16 (m104). Generic->AS3 via uintptr (low 32 = LDS off).
#if defined(__has_builtin)
#if __has_builtin(__builtin_amdgcn_global_load_lds)
#define HAVE_GLL 1
#endif
#endif
__device__ __forceinline__ void dma16(const void* g, void* lds_base, int lane) {
#ifdef HAVE_GLL
    __builtin_amdgcn_global_load_lds(
        (const __attribute__((address_space(1))) unsigned*)(unsigned long long)g,
        (__attribute__((address_space(3))) unsigned*)(unsigned)(unsigned long long)lds_base,
        16, 0, 0);
#else
    *(uint4*)((char*)lds_base + lane * 16) = *(const uint4*)g;
#endif
}

// Q pre-scale: 1/sqrt(H) * log2(e)  (attn softmax runs in exp2 domain)
#define QSCALE (0.125f * 1.44269504f)

// wf chunk byte size: 3 mats * 4 n-tiles * 64 lanes * 16 B = 12288 B
#define WF_CHUNK_BYTES 12288

// ---------------- Phase 0: W -> fragment-major swizzled W^T (bf16) ----------
// wf layout: [c(32 k-chunks)][m(3)][n(4 h-tiles)][lane(64)][j(8)]
// region (c, j=m*4+n) is 1 KB contiguous => DMA-able straight into LDS.
__global__ __launch_bounds__(256)
void wprep_kernel(const float* __restrict__ Wq,
                  const float* __restrict__ Wk,
                  const float* __restrict__ Wv,
                  unsigned short* __restrict__ wf)
{
    const int c = blockIdx.x / 3;
    const int m = blockIdx.x % 3;
    const float* W = (m == 0) ? Wq : (m == 1 ? Wk : Wv);
    const float scale = (m == 0) ? QSCALE : 1.0f;

    const int n    = threadIdx.x >> 6;
    const int lane = threadIdx.x & 63;
    const int quad = lane >> 4;
    const int col  = lane & 15;
    const int h    = n * 16 + col;

    unsigned short tmp[8];
#pragma unroll
    for (int j = 0; j < 8; ++j)
        tmp[j] = f2bfu(W[(c * 32 + quad * 8 + j) * H_ + h] * scale);
    *(uint4*)&wf[(((c * 3 + m) * 4 + n) * 64 + lane) * 8] = *(uint4*)tmp;
}

// ---------------- Phase 1: QKV projection, wave-private DMA ----------------
// Block = 32 tokens, 4 waves, grid 512 (2 blocks/CU).
// Wave w owns (mat,n) tiles j = 3w..3w+2 for BOTH 16-token halves (6 acc).
// => wave w consumes exactly the 6 wf regions it DMAs itself, so wf sync is
// a per-wave counted s_waitcnt vmcnt(8) (6 next-pair DMAs + 2 x loads stay
// in flight) and the barrier (x-transpose LDS only) is raw s_barrier +
// lgkmcnt(0) — NO vmcnt(0) drain anywhere in the loop.
__global__ __launch_bounds__(256, 2)
void qkv_kernel(const float* __restrict__ x,
                const unsigned short* __restrict__ wf,
                unsigned short* __restrict__ qb,
                unsigned short* __restrict__ kf,
                unsigned short* __restrict__ vf)
{
    __shared__ __align__(16) char           wfs[2][2 * WF_CHUNK_BYTES];  // 48 KB
    __shared__ __align__(16) unsigned short xs[2][32 * 72];              // 9 KB

    const int tid  = threadIdx.x;
    const int w    = tid >> 6;
    const int lane = tid & 63;
    const int quad = lane >> 4;
    const int col  = lane & 15;
    const long r0  = (long)blockIdx.x * 32;

    f32x4 acc[2][3];
#pragma unroll
    for (int mt = 0; mt < 2; ++mt)
#pragma unroll
        for (int i = 0; i < 3; ++i) acc[mt][i] = (f32x4){0.f, 0.f, 0.f, 0.f};

    const char* wfb = (const char*)wf;
    const int jb = w * 3;            // first owned tile index (0,3,6,9)

    // x staging: thread t handles token row t>>3, k-cols (t&7)*8 .. +7
    const int row = tid >> 3;
    const int kc  = (tid & 7) * 8;
    const float* xp = x + (r0 + row) * E_ + kc;

    // ---- prologue (DMAs issued LAST so vmcnt counting stays uniform) ----
    float4 xa[2], xb[2];
    xa[0] = *(const float4*)xp;
    xa[1] = *(const float4*)(xp + 4);
    {
        unsigned u[4] = { pk2(xa[0].x, xa[0].y), pk2(xa[0].z, xa[0].w),
                          pk2(xa[1].x, xa[1].y), pk2(xa[1].z, xa[1].w) };
        *(uint4*)&xs[0][row * 72 + kc] = *(uint4*)u;
    }
    xa[0] = *(const float4*)(xp + 64);
    xa[1] = *(const float4*)(xp + 68);
    xb[0] = xa[0]; xb[1] = xa[1];

#pragma unroll
    for (int kk2 = 0; kk2 < 2; ++kk2)
#pragma unroll
        for (int i = 0; i < 3; ++i)
            dma16(wfb + (long)kk2 * WF_CHUNK_BYTES + (jb + i) * 1024 + lane * 16,
                  &wfs[0][(kk2 * 12 + jb + i) * 1024], lane);

    for (int c = 0; c < 16; ++c) {
        const int buf = c & 1;
        // barrier for the x-transpose LDS only: drain LDS ops, not VMEM
        asm volatile("s_waitcnt lgkmcnt(0)" ::: "memory");
        __builtin_amdgcn_s_barrier();

        // issue next chunk-pair's 6 wave-private DMAs (one full iter of slack)
        if (c + 1 < 16) {
#pragma unroll
            for (int kk2 = 0; kk2 < 2; ++kk2)
#pragma unroll
                for (int i = 0; i < 3; ++i)
                    dma16(wfb + (long)(2 * (c + 1) + kk2) * WF_CHUNK_BYTES + (jb + i) * 1024 + lane * 16,
                          &wfs[buf ^ 1][(kk2 * 12 + jb + i) * 1024], lane);
        }
        if (c + 2 < 16) {             // x global prefetch, ~1.5 iterations ahead
            xb[0] = *(const float4*)(xp + (c + 2) * 64);
            xb[1] = *(const float4*)(xp + (c + 2) * 64 + 4);
        }

        // counted wait: this wave's pair-c DMAs done; newest (6 DMA + 2 x) fly on
        if (c < 14)       asm volatile("s_waitcnt vmcnt(8)" ::: "memory");
        else if (c == 14) asm volatile("s_waitcnt vmcnt(6)" ::: "memory");
        else              asm volatile("s_waitcnt vmcnt(0)" ::: "memory");

        // compute: 2 kk-halves x 2 token-tiles x 3 owned tiles
#pragma unroll
        for (int kk = 0; kk < 2; ++kk) {
#pragma unroll
            for (int mt = 0; mt < 2; ++mt) {
                bf16x8 af = *(const bf16x8*)&xs[buf][(mt * 16 + col) * 72 + kk * 32 + quad * 8];
#pragma unroll
                for (int i = 0; i < 3; ++i) {
                    bf16x8 bm = *(const bf16x8*)&wfs[buf][(kk * 12 + jb + i) * 1024 + lane * 16];
                    acc[mt][i] = __builtin_amdgcn_mfma_f32_16x16x32_bf16(af, bm, acc[mt][i], 0, 0, 0);
                }
            }
        }

        if (c + 1 < 16) {             // write x(c+1) into the other buffer
            unsigned u[4] = { pk2(xa[0].x, xa[0].y), pk2(xa[0].z, xa[0].w),
                              pk2(xa[1].x, xa[1].y), pk2(xa[1].z, xa[1].w) };
            *(uint4*)&xs[buf ^ 1][row * 72 + kc] = *(uint4*)u;
        }
        xa[0] = xb[0]; xa[1] = xb[1];
    }

    // epilogue: acc element = D[token = r0+mt*16+quad*4+r][h = (j&3)*16+col]
#pragma unroll
    for (int i = 0; i < 3; ++i) {
        const int j   = jb + i;           // tile 0..11 = mat*4 + n (wave-uniform)
        const int mat = j >> 2;
        const int h   = (j & 3) * 16 + col;
#pragma unroll
        for (int mt = 0; mt < 2; ++mt) {
#pragma unroll
            for (int r = 0; r < 4; ++r) {
                long t = r0 + mt * 16 + quad * 4 + r;   // global token (incl. batch)
                unsigned short val = f2bfu(acc[mt][i][r]);
                if (mat == 0) {
                    qb[t * H_ + h] = val;               // scale folded into Wq
                } else if (mat == 1) {
                    // fragment-major K
                    long t16 = t >> 4;  int cc = (int)(t & 15);
                    int half = h >> 5, qq = (h >> 3) & 3, jj = h & 7;
                    kf[((t16 * 2 + half) * 64 + qq * 16 + cc) * 8 + jj] = val;
                } else {
                    // fragment-major V (transposed consumption)
                    long sg = t >> 6;
                    int hi = (int)((t >> 5) & 1), q2 = (int)((t >> 3) & 3), j2 = (int)(t & 7);
                    int n2 = h >> 4, c2 = h & 15;
                    vf[(((sg * 4 + n2) * 2 + hi) * 64 + q2 * 16 + c2) * 8 + j2] = val;
                }
            }
        }
    }
}

// ---------------- Phase 2: split-K flash attention (swapped QK^T, O^T PV) --
// Grid = 1024: block (b = bid&7 -> XCD pin, qt = 127 - bid>>3, heavy first).
// 256 threads = 4 waves = 4 split-K groups; wave g: key-tiles s = g, g+4, ...
// S^T = mfma(K, Q): lane holds S[key=kt*16+quad*4+r][q=col] -> softmax
// reduce = in-lane + 2 shfl. PV computed transposed: O^T = mfma(V^T, P).
// K/V read from FRAGMENT-MAJOR buffers: every load is base + lane*16 ->
// contiguous 1KB per wave instr (16 cachelines, not 64).
#define PSS 72

__global__ __launch_bounds__(256, 4)
void attn_kernel(const unsigned short* __restrict__ qb,
                 const unsigned short* __restrict__ kf,
                 const unsigned short* __restrict__ vf,
                 float* __restrict__ out)
{
    // overlay: ps (9 KB, K-loop) shares space with oc (17 KB, combine)
    __shared__ __align__(16) char smem[4 * 64 * 17 * 4 + 4 * 2 * 16 * 4];  // 17.9 KB
    unsigned short* ps = (unsigned short*)smem;               // [4][16 q][PSS key]
    float* oc = (float*)smem;                                 // [4][64 h][17 q-pad]
    float* ml = (float*)(smem + 4 * 64 * 17 * 4);             // [4][2][16]

    const int tid  = threadIdx.x;
    const int g    = tid >> 6;        // wave = split-K group (0..3)
    const int lane = tid & 63;
    const int quad = lane >> 4;
    const int col  = lane & 15;
    const int b    = blockIdx.x & 7;        // batch -> XCD pinning
    const int qt   = 127 - (blockIdx.x >> 3); // heavy q-tiles dispatch first
    const int nt   = (qt + 4) >> 2;         // ceil((qt+1)/4) key tiles

    const unsigned short* qbb = qb + (long)b * T_ * H_;
    const unsigned short* kfb = kf + (long)b * 128 * 2 * 512;  // 128 t16 x 2 half x 512
    const unsigned short* vfb = vf + (long)b * 32 * 4 * 2 * 512; // 32 s x 4 n x 2 hi x 512

    // Q fragment: Q[q=col][d=quad*8+j] — valid as either A or B operand
    bf16x8 qa0 = *(const bf16x8*)&qbb[(qt * 16 + col) * H_ + quad * 8];
    bf16x8 qa1 = *(const bf16x8*)&qbb[(qt * 16 + col) * H_ + 32 + quad * 8];

    f32x4 o[4];                       // O^T: o[n][r] = O[q=col][h=n*16+quad*4+r]
    float m_i = -1e30f, l_i = 0.f;    // per-lane: q-row = col
#pragma unroll
    for (int n = 0; n < 4; ++n) o[n] = (f32x4){0.f, 0.f, 0.f, 0.f};

    // K fragment prefetch for first tile (coalesced: base + lane*16)
    bf16x8 kr[8];
    if (g < nt) {
#pragma unroll
        for (int kt = 0; kt < 4; ++kt) {
            const unsigned short* kp = kfb + ((long)(g * 4 + kt) * 2) * 512 + lane * 8;
            kr[kt * 2]     = *(const bf16x8*)kp;
            kr[kt * 2 + 1] = *(const bf16x8*)(kp + 512);
        }
    }

    for (int s = g; s < nt; s += 4) {
        // S^T = K Q^T : sa[kt][r] = S[key = s*64 + kt*16 + quad*4 + r][q = col]
        f32x4 sa[4];
#pragma unroll
        for (int kt = 0; kt < 4; ++kt) {
            sa[kt] = (f32x4){0.f, 0.f, 0.f, 0.f};
            sa[kt] = __builtin_amdgcn_mfma_f32_16x16x32_bf16(kr[kt * 2],     qa0, sa[kt], 0, 0, 0);
            sa[kt] = __builtin_amdgcn_mfma_f32_16x16x32_bf16(kr[kt * 2 + 1], qa1, sa[kt], 0, 0, 0);
        }

        // hoist V(s) loads: ~softmax-duration ahead of the PV use (coalesced)
        // vr[n*2+hi] lane(q,c)[j] = V[t=s*64+hi*32+q*8+j][h=n*16+c]
        bf16x8 vr[8];
#pragma unroll
        for (int n = 0; n < 4; ++n) {
            const unsigned short* vp = vfb + ((long)(s * 4 + n) * 2) * 512 + lane * 8;
            vr[n * 2]     = *(const bf16x8*)vp;
            vr[n * 2 + 1] = *(const bf16x8*)(vp + 512);
        }

        // prefetch next tile's K (overlaps softmax + PV below)
        if (s + 4 < nt) {
#pragma unroll
            for (int kt = 0; kt < 4; ++kt) {
                const unsigned short* kp = kfb + ((long)((s + 4) * 4 + kt) * 2) * 512 + lane * 8;
                kr[kt * 2]     = *(const bf16x8*)kp;
                kr[kt * 2 + 1] = *(const bf16x8*)(kp + 512);
            }
        }

        if (s == nt - 1) {            // diagonal tile: causal mask
            const int qg = qt * 16 + col;
#pragma unroll
            for (int kt = 0; kt < 4; ++kt)
#pragma unroll
                for (int r = 0; r < 4; ++r) {
                    int kg = s * 64 + kt * 16 + quad * 4 + r;
                    if (kg > qg) sa[kt][r] = -1e30f;
                }
        }

        // online softmax: in-lane over 16 keys, then 2 shfl rounds (quads)
        float mx = fmaxf(
            fmaxf(fmaxf(fmaxf(sa[0][0], sa[0][1]), fmaxf(sa[0][2], sa[0][3])),
                  fmaxf(fmaxf(sa[1][0], sa[1][1]), fmaxf(sa[1][2], sa[1][3]))),
            fmaxf(fmaxf(fmaxf(sa[2][0], sa[2][1]), fmaxf(sa[2][2], sa[2][3])),
                  fmaxf(fmaxf(sa[3][0], sa[3][1]), fmaxf(sa[3][2], sa[3][3]))));
        mx = fmaxf(mx, __shfl_xor(mx, 16, 64));
        mx = fmaxf(mx, __shfl_xor(mx, 32, 64));

        const float mnew  = fmaxf(m_i, mx);
        const float alpha = __builtin_amdgcn_exp2f(m_i - mnew);
        m_i = mnew;

        // P = exp2(S - m); write [q][key] rows: 4x ds_write_b64
        float rs = 0.f;
#pragma unroll
        for (int kt = 0; kt < 4; ++kt) {
            float pv0 = __builtin_amdgcn_exp2f(sa[kt][0] - mnew);
            float pv1 = __builtin_amdgcn_exp2f(sa[kt][1] - mnew);
            float pv2 = __builtin_amdgcn_exp2f(sa[kt][2] - mnew);
            float pv3 = __builtin_amdgcn_exp2f(sa[kt][3] - mnew);
            rs += (pv0 + pv1) + (pv2 + pv3);
            uint2 u = { pk2(pv0, pv1), pk2(pv2, pv3) };
            *(uint2*)&ps[g * 16 * PSS + col * PSS + kt * 16 + quad * 4] = u;
        }
        rs += __shfl_xor(rs, 16, 64);
        rs += __shfl_xor(rs, 32, 64);
        l_i = l_i * alpha + rs;

        // rescale O^T: alpha is per-q = per-lane (col) — no shfl needed
#pragma unroll
        for (int n = 0; n < 4; ++n)
#pragma unroll
            for (int r = 0; r < 4; ++r)
                o[n][r] *= alpha;

        // O^T += V^T P^T : A = V^T (regs), B = P[q=col][k] from per-wave LDS
        bf16x8 pa0 = *(const bf16x8*)&ps[g * 16 * PSS + col * PSS + quad * 8];
        bf16x8 pa1 = *(const bf16x8*)&ps[g * 16 * PSS + col * PSS + 32 + quad * 8];
#pragma unroll
        for (int n = 0; n < 4; ++n) {
            o[n] = __builtin_amdgcn_mfma_f32_16x16x32_bf16(vr[n * 2],     pa0, o[n], 0, 0, 0);
            o[n] = __builtin_amdgcn_mfma_f32_16x16x32_bf16(vr[n * 2 + 1], pa1, o[n], 0, 0, 0);
        }
    }

    // ---- split-K combine (oc overlays ps -> barrier first) ----
    __syncthreads();
#pragma unroll
    for (int n = 0; n < 4; ++n)
#pragma unroll
        for (int r = 0; r < 4; ++r)
            oc[(g * 64 + n * 16 + quad * 4 + r) * 17 + col] = o[n][r];
    if (quad == 0) {                  // m/l live at q = col
        ml[(g * 2 + 0) * 16 + col] = m_i;
        ml[(g * 2 + 1) * 16 + col] = l_i;
    }
    __syncthreads();

    // merge: wave g owns q-rows g*4 .. g*4+3; lane = h (0..63)
#pragma unroll
    for (int rr = 0; rr < 4; ++rr) {
        int row = g * 4 + rr;
        float M = ml[0 * 32 + row];
#pragma unroll
        for (int j = 1; j < 4; ++j) M = fmaxf(M, ml[j * 32 + row]);
        float lsum = 0.f, osum = 0.f;
#pragma unroll
        for (int j = 0; j < 4; ++j) {
            float wgt = __builtin_amdgcn_exp2f(ml[j * 32 + row] - M);
            lsum += ml[j * 32 + 16 + row] * wgt;
            osum += oc[(j * 64 + lane) * 17 + row] * wgt;
        }
        out[((long)b * T_ + qt * 16 + row) * H_ + lane] = osum / lsum;
    }
}

extern "C" void kernel_launch(void* const* d_in, const int* in_sizes, int n_in,
                              void* d_out, int out_size, void* d_ws, size_t ws_size,
                              hipStream_t stream) {
    (void)in_sizes; (void)n_in; (void)out_size; (void)ws_size;
    const float* x  = (const float*)d_in[0];
    const float* Wq = (const float*)d_in[1];
    const float* Wk = (const float*)d_in[2];
    const float* Wv = (const float*)d_in[3];

    unsigned short* qb = (unsigned short*)d_ws;                // 2 MB row-major Q
    unsigned short* kf = qb + (size_t)BT_ * H_;                // 2 MB fragment-major K
    unsigned short* vf = kf + (size_t)BT_ * H_;                // 2 MB fragment-major V
    unsigned short* wf = vf + (size_t)BT_ * H_;                // 384 KB fragment-major W

    wprep_kernel<<<96, 256, 0, stream>>>(Wq, Wk, Wv, wf);
    qkv_kernel<<<BT_ / 32, 256, 0, stream>>>(x, wf, qb, kf, vf);
    attn_kernel<<<B_ * 128, 256, 0, stream>>>(qb, kf, vf, (float*)d_out);
}